// Round 7
// baseline (369.803 us; speedup 1.0000x reference)
//
#include <hip/hip_runtime.h>
#include <cstdint>
#include <cstddef>

#define B_N 4096
typedef short short8 __attribute__((ext_vector_type(8)));
typedef float f32x4 __attribute__((ext_vector_type(4)));

// ws layout (float units)
static constexpr size_t H2B_OFF    = 0;                                  // 4096*4096 ushort
static constexpr size_t POOLED_OFF = 8388608;                            // B*16 f
static constexpr size_t EIDX_OFF   = POOLED_OFF + (size_t)B_N * 16;      // B int
static constexpr size_t EW_OFF     = EIDX_OFF + B_N;                     // B f
static constexpr size_t ORDER_OFF  = EW_OFF + B_N;                       // 4*B int
static constexpr size_t CNT_OFF    = ORDER_OFF + (size_t)4 * B_N;        // 4 int
static constexpr size_t PSUM_OFF   = CNT_OFF + 4;                        // 4 f
static constexpr size_t W2R_OFF    = PSUM_OFF + 4;                       // 73728 ushort = 36864 f
static constexpr size_t W1R_OFF    = W2R_OFF + 36864;                    // 2097152 ushort = 1048576 f
static constexpr size_t W1C_OFF    = W1R_OFF + 1048576;                  // 4096 ushort = 2048 f
static constexpr size_t F1_OFF     = W1C_OFF + 2048;                     // 4096*128 f

__device__ __forceinline__ unsigned int f2bf(float f) {
  unsigned int u = __float_as_uint(f);
  return (u + 0x7fffu + ((u >> 16) & 1u)) >> 16;   // RNE bf16
}

// ---------------- K0: merged repack (fc1 w -> bf16, conv2 w -> bf16 [e][s][oc][ic],
//                      conv1 w -> B-frag layout) + zero counts/psum ----------------
__global__ __launch_bounds__(256) void k_repack_all(
    const float* __restrict__ wfc1, unsigned short* __restrict__ w1r,
    const float* __restrict__ wc2, unsigned short* __restrict__ w2r,
    const float* __restrict__ wc1, unsigned short* __restrict__ w1c,
    int* __restrict__ counts) {
  const int bid = blockIdx.x, t = threadIdx.x;
  if (bid < 2048) {
    const int i = bid * 256 + t;                     // float4 index
    const float4 v = ((const float4*)wfc1)[i];
    ushort4 u;
    u.x = (unsigned short)f2bf(v.x); u.y = (unsigned short)f2bf(v.y);
    u.z = (unsigned short)f2bf(v.z); u.w = (unsigned short)f2bf(v.w);
    *(ushort4*)(w1r + 4 * (size_t)i) = u;
  } else if (bid < 2336) {
    if (bid == 2048 && t < 8) counts[t] = 0;         // counts[4] + psum[4]
    const int i = (bid - 2048) * 256 + t;
    if (i < 4 * 9 * 64 * 32) {
      const int ic = i & 31, j = i >> 5;
      const int oc = j & 63, j2 = j >> 6;
      const int s = j2 % 9, e = j2 / 9;
      w2r[i] = (unsigned short)f2bf(wc2[(((size_t)e * 64 + oc) * 32 + ic) * 9 + s]);
    }
  } else {
    const int i = (bid - 2336) * 256 + t;            // [0, 4096)
    if (i < 4096) {
      const int j = i & 7, n16 = (i >> 3) & 15, q = (i >> 7) & 3, nt = (i >> 9) & 1, e = i >> 10;
      const int k = q * 8 + j;
      float v = 0.f;
      if (k < 27) {
        const int ky = k / 9, c = k % 9, kx = c / 3, ic = c % 3;
        v = wc1[((e * 32 + nt * 16 + n16) * 3 + ic) * 9 + ky * 3 + kx];
      }
      w1c[i] = (unsigned short)f2bf(v);
    }
  }
}

// ---------------- K1: router conv(3->16,SAME)+relu+GAP — fp32, SGPR weights ----------------
__global__ __launch_bounds__(256) void k_router_conv(const float* __restrict__ x,
    const float* __restrict__ gw, const float* __restrict__ gb,
    float* __restrict__ pooled) {
  __shared__ __align__(16) float xpad[3 * 34 * 34];   // 13872 B
  __shared__ float red[16 * 33];
  const int b = blockIdx.x, t = threadIdx.x;
  for (int i = t; i < 867; i += 256) ((uint4*)xpad)[i] = make_uint4(0, 0, 0, 0);
  __syncthreads();
  const float4* x4 = (const float4*)(x + (size_t)b * 3072);
  for (int i = t; i < 768; i += 256) {
    float4 v = x4[i];
    int flat = i * 4, ic = flat >> 10, rem = flat & 1023, row = rem >> 5, col = rem & 31;
    float* d = &xpad[ic * 1156 + (row + 1) * 34 + (col + 1)];
    d[0] = v.x; d[1] = v.y; d[2] = v.z; d[3] = v.w;
  }
  __syncthreads();
  const int ty = t >> 4, tx = t & 15;
  float win[3][4][4];
#pragma unroll
  for (int ic = 0; ic < 3; ++ic)
#pragma unroll
  for (int rr = 0; rr < 4; ++rr) {
    const float2* p = (const float2*)&xpad[ic * 1156 + (2 * ty + rr) * 34 + 2 * tx];
    float2 a = p[0], c = p[1];
    win[ic][rr][0] = a.x; win[ic][rr][1] = a.y; win[ic][rr][2] = c.x; win[ic][rr][3] = c.y;
  }
  float sums[16];
#pragma unroll
  for (int oc = 0; oc < 16; ++oc) {
    const float bias = gb[oc];
    float a00 = bias, a01 = bias, a10 = bias, a11 = bias;
#pragma unroll
    for (int ic = 0; ic < 3; ++ic)
#pragma unroll
    for (int ky = 0; ky < 3; ++ky)
#pragma unroll
    for (int kx = 0; kx < 3; ++kx) {
      const float wv = gw[oc * 27 + ic * 9 + ky * 3 + kx];   // block-uniform -> SGPR
      a00 += wv * win[ic][ky][kx];     a01 += wv * win[ic][ky][kx + 1];
      a10 += wv * win[ic][ky + 1][kx]; a11 += wv * win[ic][ky + 1][kx + 1];
    }
    sums[oc] = fmaxf(a00, 0.f) + fmaxf(a01, 0.f) + fmaxf(a10, 0.f) + fmaxf(a11, 0.f);
  }
  const int lane = t & 63, wid = t >> 6;
#pragma unroll
  for (int oc = 0; oc < 16; ++oc) {
    float s = sums[oc];
    s += __shfl_xor(s, 1);
    s += __shfl_xor(s, 2);
    s += __shfl_xor(s, 4);
    sums[oc] = s;
  }
  if ((lane & 7) == 0) {
    const int slot = wid * 8 + (lane >> 3);
#pragma unroll
    for (int oc = 0; oc < 16; ++oc) red[oc * 33 + slot] = sums[oc];
  }
  __syncthreads();
  if (t < 16) {
    float s = 0.f;
#pragma unroll
    for (int i = 0; i < 32; ++i) s += red[t * 33 + i];
    pooled[(size_t)b * 16 + t] = s * (1.f / 1024.f);
  }
}

// ---------------- K2: router FC + softmax + top-1 + bucketing + prob sums ----------------
__global__ __launch_bounds__(256) void k_router_fc(const float* __restrict__ pooled,
    const float* __restrict__ gwfc, const float* __restrict__ gbfc,
    float* __restrict__ probs_out, int* __restrict__ eidx, float* __restrict__ ew,
    int* __restrict__ counts, int* __restrict__ order, float* __restrict__ psum) {
  __shared__ float ps[4];
  const int t = threadIdx.x;
  const int b = blockIdx.x * 256 + t;
  if (t < 4) ps[t] = 0.f;
  __syncthreads();
  const float* pl = pooled + (size_t)b * 16;
  float l[4];
#pragma unroll
  for (int j = 0; j < 4; ++j) {
    float s = gbfc[j];
#pragma unroll
    for (int i = 0; i < 16; ++i) s += pl[i] * gwfc[j * 16 + i];
    l[j] = s;
  }
  const float mx = fmaxf(fmaxf(l[0], l[1]), fmaxf(l[2], l[3]));
  float ex[4], ssum = 0.f;
#pragma unroll
  for (int j = 0; j < 4; ++j) { ex[j] = expf(l[j] - mx); ssum += ex[j]; }
  const float inv = 1.f / ssum;
  float p[4];
#pragma unroll
  for (int j = 0; j < 4; ++j) p[j] = ex[j] * inv;
  *(float4*)(probs_out + (size_t)b * 4) = make_float4(p[0], p[1], p[2], p[3]);
  int em = 0; float pm = p[0];
#pragma unroll
  for (int j = 1; j < 4; ++j) if (p[j] > pm) { pm = p[j]; em = j; }
  eidx[b] = em; ew[b] = pm;
  const int slot = atomicAdd(&counts[em], 1);
  order[em * B_N + slot] = b;
#pragma unroll
  for (int j = 0; j < 4; ++j) atomicAdd(&ps[j], p[j]);
  __syncthreads();
  if (t < 4) atomicAdd(&psum[t], ps[t]);
}

// ---- conv1 A-fragment gather from ic-interleaved bf16 image (no convert in loop) ----
__device__ __forceinline__ short8 gather_b(const unsigned short* __restrict__ base,
                                           const int* goff, bool isq1, bool isq3) {
  const unsigned lo0 = base[goff[0]];
  const unsigned hi0 = isq1 ? base[102] : base[goff[0] + 1];   // patch p=9 (row1,c0)
  const unsigned lo1 = base[goff[1]];
  const unsigned hi1 = base[goff[1] + 1];
  const unsigned lo2 = base[goff[2]];
  const unsigned hi2 = base[goff[2] + 1];
  const unsigned lo3 = base[goff[3]];
  const unsigned hi3 = base[goff[3] + 1];
  union { unsigned u[4]; short8 s; } r;
  r.u[0] = lo0 | (hi0 << 16);
  r.u[1] = isq3 ? lo1 : (lo1 | (hi1 << 16));   // k>=27 zero padding
  r.u[2] = isq3 ? 0u : (lo2 | (hi2 << 16));
  r.u[3] = isq3 ? 0u : (lo3 | (hi3 << 16));
  return r.s;
}

// ---------------- K3: conv1 MFMA (im2col, bf16-staged x) -> h1 bf16 LDS -> conv2 MFMA -> h2 bf16 ----------------
__global__ __launch_bounds__(256, 3) void k_experts_conv(const float* __restrict__ x,
    const unsigned short* __restrict__ w1c, const float* __restrict__ b1g,
    const unsigned short* __restrict__ w2r, const float* __restrict__ b2g,
    const int* __restrict__ eidx, unsigned short* __restrict__ h2b) {
  __shared__ __align__(16) unsigned short xpi[3472];         // [34 rows][34 cols][3 ic] bf16, 6944 B
  __shared__ __align__(16) unsigned short h1s[18 * 18 * 32]; // 20736 B (reused as h2s fp32 [64][68])
  const int b = blockIdx.x, t = threadIdx.x;
  const int e = __builtin_amdgcn_readfirstlane(eidx[b]);
  {
    uint4 z4 = make_uint4(0, 0, 0, 0);
    uint4* z1 = (uint4*)h1s;
    for (int i = t; i < 1296; i += 256) z1[i] = z4;
    uint4* z2 = (uint4*)xpi;
    for (int i = t; i < 434; i += 256) z2[i] = z4;
  }
  __syncthreads();
  const float4* x4 = (const float4*)(x + (size_t)b * 3072);
  for (int i = t; i < 768; i += 256) {
    float4 v = x4[i];
    int flat = i * 4, ic = flat >> 10, rem = flat & 1023, row = rem >> 5, col = rem & 31;
    unsigned short* d = &xpi[(row + 1) * 102 + (col + 1) * 3 + ic];
    d[0] = (unsigned short)f2bf(v.x); d[3] = (unsigned short)f2bf(v.y);
    d[6] = (unsigned short)f2bf(v.z); d[9] = (unsigned short)f2bf(v.w);
  }
  __syncthreads();
  const int lane = t & 63, wv = t >> 6;
  const int n16 = lane & 15, q = lane >> 4;
  // ---- conv1: MFMA 16x16x32, K=27(+pad), M=pixel col, N=32 oc ----
  {
    const bool isq1 = (q == 1), isq3 = (q == 3);
    const short8 wb0 = *(const short8*)(w1c + (((e * 2 + 0) * 4 + q) * 16 + n16) * 8);
    const short8 wb1 = *(const short8*)(w1c + (((e * 2 + 1) * 4 + q) * 16 + n16) * 8);
    const float bias0 = b1g[e * 32 + n16];
    const float bias1 = b1g[e * 32 + 16 + n16];
    int goff[4];
#pragma unroll
    for (int t4 = 0; t4 < 4; ++t4) {
      const int p0 = q * 8 + 2 * t4;
      const int r = (p0 * 939) >> 13;        // p0/9 for p0<32
      goff[t4] = r * 102 + (p0 - 9 * r);
    }
    for (int pid = 0; pid < 8; ++pid) {
      const int pairid = wv * 8 + pid;
      const int yp = pairid >> 1, xh = pairid & 1;
      const unsigned short* baseA = &xpi[(2 * yp) * 102 + (xh * 16 + n16) * 3];
      const short8 afA = gather_b(baseA, goff, isq1, isq3);
      const short8 afB = gather_b(baseA + 102, goff, isq1, isq3);
      f32x4 aA0 = {bias0, bias0, bias0, bias0}, aA1 = {bias1, bias1, bias1, bias1};
      f32x4 aB0 = aA0, aB1 = aA1;
      aA0 = __builtin_amdgcn_mfma_f32_16x16x32_bf16(afA, wb0, aA0, 0, 0, 0);
      aA1 = __builtin_amdgcn_mfma_f32_16x16x32_bf16(afA, wb1, aA1, 0, 0, 0);
      aB0 = __builtin_amdgcn_mfma_f32_16x16x32_bf16(afB, wb0, aB0, 0, 0, 0);
      aB1 = __builtin_amdgcn_mfma_f32_16x16x32_bf16(afB, wb1, aB1, 0, 0, 0);
      // 2x2 maxpool + relu -> h1s[pix][ic] bf16
      const int px = xh * 8 + 2 * q;
      unsigned short* hw = &h1s[((yp + 1) * 18 + (px + 1)) * 32];
      const float p00 = fmaxf(fmaxf(fmaxf(aA0[0], aA0[1]), fmaxf(aB0[0], aB0[1])), 0.f);
      const float p01 = fmaxf(fmaxf(fmaxf(aA0[2], aA0[3]), fmaxf(aB0[2], aB0[3])), 0.f);
      const float p10 = fmaxf(fmaxf(fmaxf(aA1[0], aA1[1]), fmaxf(aB1[0], aB1[1])), 0.f);
      const float p11 = fmaxf(fmaxf(fmaxf(aA1[2], aA1[3]), fmaxf(aB1[2], aB1[3])), 0.f);
      hw[n16]           = (unsigned short)f2bf(p00);
      hw[16 + n16]      = (unsigned short)f2bf(p10);
      hw[32 + n16]      = (unsigned short)f2bf(p01);
      hw[32 + 16 + n16] = (unsigned short)f2bf(p11);
    }
  }
  __syncthreads();
  // ---- conv2: wave = 4 rows x all 64 oc; B streamed from global (L2) with prefetch ----
  {
    const unsigned short* wbase = w2r + (size_t)e * 18432 + n16 * 32 + q * 8;
    float bz[4];
#pragma unroll
    for (int nt = 0; nt < 4; ++nt) bz[nt] = b2g[e * 64 + nt * 16 + n16];
    f32x4 acc[4][4];
#pragma unroll
    for (int mt4 = 0; mt4 < 4; ++mt4)
#pragma unroll
      for (int nt = 0; nt < 4; ++nt) {
        acc[mt4][nt][0] = bz[nt]; acc[mt4][nt][1] = bz[nt];
        acc[mt4][nt][2] = bz[nt]; acc[mt4][nt][3] = bz[nt];
      }
    short8 Bc[4];
#pragma unroll
    for (int nt = 0; nt < 4; ++nt) Bc[nt] = *(const short8*)(wbase + nt * 512);
#pragma unroll
    for (int s = 0; s < 9; ++s) {
      const int ky = s / 3, kx = s % 3;
      short8 Bn[4];
      if (s < 8) {
#pragma unroll
        for (int nt = 0; nt < 4; ++nt)
          Bn[nt] = *(const short8*)(wbase + (s + 1) * 2048 + nt * 512);
      }
#pragma unroll
      for (int mt4 = 0; mt4 < 4; ++mt4) {
        const int mt = wv * 4 + mt4;
        const short8 af = *(const short8*)&h1s[((mt + ky) * 18 + n16 + kx) * 32 + q * 8];
#pragma unroll
        for (int nt = 0; nt < 4; ++nt)
          acc[mt4][nt] = __builtin_amdgcn_mfma_f32_16x16x32_bf16(af, Bc[nt], acc[mt4][nt], 0, 0, 0);
      }
      if (s < 8) {
#pragma unroll
        for (int nt = 0; nt < 4; ++nt) Bc[nt] = Bn[nt];
      }
    }
    __syncthreads();                        // all MFMA reads of h1s done
    float* h2s = (float*)h1s;               // [oc][68]
#pragma unroll
    for (int u2 = 0; u2 < 2; ++u2) {
      const int py = wv * 2 + u2;
#pragma unroll
      for (int nt = 0; nt < 4; ++nt) {
        const f32x4 a = acc[2 * u2][nt], c = acc[2 * u2 + 1][nt];
        float2 pv;
        pv.x = fmaxf(fmaxf(fmaxf(a[0], a[1]), fmaxf(c[0], c[1])), 0.f);
        pv.y = fmaxf(fmaxf(fmaxf(a[2], a[3]), fmaxf(c[2], c[3])), 0.f);
        *(float2*)&h2s[(nt * 16 + n16) * 68 + py * 8 + 2 * q] = pv;
      }
    }
  }
  __syncthreads();
  {
    const float* h2s = (const float*)h1s;
    unsigned short* dst = h2b + (size_t)b * 4096;
#pragma unroll
    for (int j = 0; j < 2; ++j) {
      const int f = 8 * (t + 256 * j);          // flat k = oc*64+py*8+px
      const float* src = &h2s[(f >> 6) * 68 + (f & 63)];
      float4 v0 = *(const float4*)src;
      float4 v1 = *(const float4*)(src + 4);
      unsigned int p0 = f2bf(v0.x) | (f2bf(v0.y) << 16);
      unsigned int p1 = f2bf(v0.z) | (f2bf(v0.w) << 16);
      unsigned int p2 = f2bf(v1.x) | (f2bf(v1.y) << 16);
      unsigned int p3 = f2bf(v1.z) | (f2bf(v1.w) << 16);
      *(uint4*)(dst + f) = make_uint4(p0, p1, p2, p3);
    }
  }
}

// ---------------- K4a: fc1 via bf16 MFMA, N-split (block = 16 samples x 64 oc), f1 -> global ----------------
__global__ __launch_bounds__(256) void k_fc1(const unsigned short* __restrict__ h2b,
    const unsigned short* __restrict__ w1r, const float* __restrict__ b1g,
    const int* __restrict__ counts, const int* __restrict__ order,
    float* __restrict__ f1g) {
  const int bid = blockIdx.x;
  const int e = bid >> 9, half = (bid >> 8) & 1, tile = bid & 255;
  const int n = counts[e];
  const int base = tile * 16;
  if (base >= n) return;
  const int t = threadIdx.x;
  __shared__ int sb[16];
  __shared__ __align__(16) unsigned short As[16][264];   // 16 samples x 256 k, +8 pad
  if (t < 16) {
    const int idx = base + t;
    sb[t] = order[e * B_N + ((idx < n) ? idx : base)];
  }
  __syncthreads();
  const int lane = t & 63, wv = t >> 6;
  const int n16 = lane & 15, q = lane >> 4;
  const int oc = half * 64 + wv * 16 + n16;
  const unsigned short* wb = w1r + ((size_t)(e * 128 + oc)) * 4096 + q * 8;
  f32x4 acc = {0.f, 0.f, 0.f, 0.f};
  const int ldrow = t >> 4, ldseg = t & 15;
  for (int kc = 0; kc < 4096; kc += 256) {
    {
      const unsigned short* src = h2b + (size_t)sb[ldrow] * 4096 + kc;
      uint4 v0 = *(const uint4*)(src + ldseg * 8);
      uint4 v1 = *(const uint4*)(src + (ldseg + 16) * 8);
      *(uint4*)&As[ldrow][ldseg * 8] = v0;
      *(uint4*)&As[ldrow][(ldseg + 16) * 8] = v1;
    }
    __syncthreads();
#pragma unroll
    for (int ks = 0; ks < 8; ++ks) {
      const short8 af = *(const short8*)&As[n16][ks * 32 + q * 8];   // A[m=n16][k]
      const short8 bf = *(const short8*)(wb + kc + ks * 32);         // B[k][n=oc]
      acc = __builtin_amdgcn_mfma_f32_16x16x32_bf16(af, bf, acc, 0, 0, 0);
    }
    __syncthreads();
  }
  // C layout: row m = q*4+r (sample), col = n16 (oc) -> relu(+bias) -> f1 global
  const float bb = b1g[e * 128 + oc];
#pragma unroll
  for (int r = 0; r < 4; ++r) {
    const int m = q * 4 + r;
    f1g[(size_t)sb[m] * 128 + oc] = fmaxf(acc[r] + bb, 0.f);
  }
}

// ---------------- K4b: fc2 (10x128 dot per sample) * router weight + aux loss ----------------
__global__ __launch_bounds__(256) void k_fc2(const float* __restrict__ f1g,
    const float* __restrict__ w2g, const float* __restrict__ b2g,
    const int* __restrict__ eidx, const float* __restrict__ ew,
    const float* __restrict__ psum, float* __restrict__ outp) {
  const int idx = blockIdx.x * 256 + threadIdx.x;    // [0, 40960)
  if (idx == 0) {
    float a = 0.f;
#pragma unroll
    for (int j = 0; j < 4; ++j) {
      const float mp = psum[j] * (1.f / 4096.f) - 0.25f;
      a += mp * mp;
    }
    outp[57344] = a * 0.25f;                         // aux loss
  }
  const int s = idx / 10, o = idx - s * 10;
  const int e = eidx[s];
  const float* f1 = f1g + (size_t)s * 128;
  const float* w2 = w2g + (e * 10 + o) * 128;
  float acc = b2g[e * 10 + o];
#pragma unroll 8
  for (int c = 0; c < 128; c += 4) {
    const float4 a = *(const float4*)(f1 + c);
    const float4 w = *(const float4*)(w2 + c);
    acc += a.x * w.x + a.y * w.y + a.z * w.z + a.w * w.w;
  }
  outp[idx] = acc * ew[s];
}

extern "C" void kernel_launch(void* const* d_in, const int* in_sizes, int n_in,
                              void* d_out, int out_size, void* d_ws, size_t ws_size,
                              hipStream_t stream) {
  const float* x        = (const float*)d_in[0];
  const float* gw_conv  = (const float*)d_in[1];
  const float* gb_conv  = (const float*)d_in[2];
  const float* gw_fc    = (const float*)d_in[3];
  const float* gb_fc    = (const float*)d_in[4];
  const float* ew_conv1 = (const float*)d_in[5];
  const float* eb_conv1 = (const float*)d_in[6];
  const float* ew_conv2 = (const float*)d_in[7];
  const float* eb_conv2 = (const float*)d_in[8];
  const float* ew_fc1   = (const float*)d_in[9];
  const float* eb_fc1   = (const float*)d_in[10];
  const float* ew_fc2   = (const float*)d_in[11];
  const float* eb_fc2   = (const float*)d_in[12];
  float* out = (float*)d_out;
  float* ws  = (float*)d_ws;

  unsigned short* h2b = (unsigned short*)(ws + H2B_OFF);
  float* pooled = ws + POOLED_OFF;
  int*   eidx   = (int*)(ws + EIDX_OFF);
  float* ew     = ws + EW_OFF;
  int*   order  = (int*)(ws + ORDER_OFF);
  int*   counts = (int*)(ws + CNT_OFF);
  float* psum   = ws + PSUM_OFF;
  unsigned short* w2r = (unsigned short*)(ws + W2R_OFF);
  unsigned short* w1r = (unsigned short*)(ws + W1R_OFF);
  unsigned short* w1c = (unsigned short*)(ws + W1C_OFF);
  float* f1g = ws + F1_OFF;

  k_repack_all<<<2352, 256, 0, stream>>>(ew_fc1, w1r, ew_conv2, w2r, ew_conv1, w1c, counts);
  k_router_conv<<<4096, 256, 0, stream>>>(x, gw_conv, gb_conv, pooled);
  k_router_fc<<<16, 256, 0, stream>>>(pooled, gw_fc, gb_fc, out + 40960, eidx, ew,
                                      counts, order, psum);
  k_experts_conv<<<4096, 256, 0, stream>>>(x, w1c, eb_conv1, w2r, eb_conv2,
                                           eidx, h2b);
  k_fc1<<<2048, 256, 0, stream>>>(h2b, w1r, eb_fc1, counts, order, f1g);
  k_fc2<<<160, 256, 0, stream>>>(f1g, ew_fc2, eb_fc2, eidx, ew, psum, out);
}

// Round 8
// 314.430 us; speedup vs baseline: 1.1761x; 1.1761x over previous
//
#include <hip/hip_runtime.h>
#include <cstdint>
#include <cstddef>

#define B_N 4096
typedef short short8 __attribute__((ext_vector_type(8)));
typedef float f32x4 __attribute__((ext_vector_type(4)));

// ws layout (float units)
static constexpr size_t H2B_OFF    = 0;                                  // 4096*4096 ushort
static constexpr size_t POOLED_OFF = 8388608;                            // B*16 f
static constexpr size_t EIDX_OFF   = POOLED_OFF + (size_t)B_N * 16;      // B int
static constexpr size_t EW_OFF     = EIDX_OFF + B_N;                     // B f
static constexpr size_t ORDER_OFF  = EW_OFF + B_N;                       // 4*B int
static constexpr size_t CNT_OFF    = ORDER_OFF + (size_t)4 * B_N;        // 4 int
static constexpr size_t PSUM_OFF   = CNT_OFF + 4;                        // 4 f
static constexpr size_t W2R_OFF    = PSUM_OFF + 4;                       // 73728 ushort = 36864 f
static constexpr size_t W1R_OFF    = W2R_OFF + 36864;                    // 2097152 ushort = 1048576 f
static constexpr size_t W1C_OFF    = W1R_OFF + 1048576;                  // 4096 ushort = 2048 f

__device__ __forceinline__ unsigned int f2bf(float f) {
  unsigned int u = __float_as_uint(f);
  return (u + 0x7fffu + ((u >> 16) & 1u)) >> 16;   // RNE bf16
}

// ---------------- K0: merged repack (fc1 w, conv2 w, conv1 w) + zero counts/psum ----------------
__global__ __launch_bounds__(256) void k_repack_all(
    const float* __restrict__ wfc1, unsigned short* __restrict__ w1r,
    const float* __restrict__ wc2, unsigned short* __restrict__ w2r,
    const float* __restrict__ wc1, unsigned short* __restrict__ w1c,
    int* __restrict__ counts) {
  const int bid = blockIdx.x, t = threadIdx.x;
  if (bid < 2048) {
    const int i = bid * 256 + t;                     // float4 index
    const float4 v = ((const float4*)wfc1)[i];
    ushort4 u;
    u.x = (unsigned short)f2bf(v.x); u.y = (unsigned short)f2bf(v.y);
    u.z = (unsigned short)f2bf(v.z); u.w = (unsigned short)f2bf(v.w);
    *(ushort4*)(w1r + 4 * (size_t)i) = u;
  } else if (bid < 2336) {
    if (bid == 2048 && t < 8) counts[t] = 0;         // counts[4] + psum[4]
    const int i = (bid - 2048) * 256 + t;
    if (i < 4 * 9 * 64 * 32) {
      const int ic = i & 31, j = i >> 5;
      const int oc = j & 63, j2 = j >> 6;
      const int s = j2 % 9, e = j2 / 9;
      w2r[i] = (unsigned short)f2bf(wc2[(((size_t)e * 64 + oc) * 32 + ic) * 9 + s]);
    }
  } else {
    const int i = (bid - 2336) * 256 + t;            // [0, 4096)
    if (i < 4096) {
      const int j = i & 7, n16 = (i >> 3) & 15, q = (i >> 7) & 3, nt = (i >> 9) & 1, e = i >> 10;
      const int k = q * 8 + j;
      float v = 0.f;
      if (k < 27) {
        const int ky = k / 9, c = k % 9, kx = c / 3, ic = c % 3;
        v = wc1[((e * 32 + nt * 16 + n16) * 3 + ic) * 9 + ky * 3 + kx];
      }
      w1c[i] = (unsigned short)f2bf(v);
    }
  }
}

// ---------------- K1: router conv(3->16,SAME)+relu+GAP — fp32, SGPR weights ----------------
__global__ __launch_bounds__(256) void k_router_conv(const float* __restrict__ x,
    const float* __restrict__ gw, const float* __restrict__ gb,
    float* __restrict__ pooled) {
  __shared__ __align__(16) float xpad[3 * 34 * 34];   // 13872 B
  __shared__ float red[16 * 33];
  const int b = blockIdx.x, t = threadIdx.x;
  for (int i = t; i < 867; i += 256) ((uint4*)xpad)[i] = make_uint4(0, 0, 0, 0);
  __syncthreads();
  const float4* x4 = (const float4*)(x + (size_t)b * 3072);
  for (int i = t; i < 768; i += 256) {
    float4 v = x4[i];
    int flat = i * 4, ic = flat >> 10, rem = flat & 1023, row = rem >> 5, col = rem & 31;
    float* d = &xpad[ic * 1156 + (row + 1) * 34 + (col + 1)];
    d[0] = v.x; d[1] = v.y; d[2] = v.z; d[3] = v.w;
  }
  __syncthreads();
  const int ty = t >> 4, tx = t & 15;
  float win[3][4][4];
#pragma unroll
  for (int ic = 0; ic < 3; ++ic)
#pragma unroll
  for (int rr = 0; rr < 4; ++rr) {
    const float2* p = (const float2*)&xpad[ic * 1156 + (2 * ty + rr) * 34 + 2 * tx];
    float2 a = p[0], c = p[1];
    win[ic][rr][0] = a.x; win[ic][rr][1] = a.y; win[ic][rr][2] = c.x; win[ic][rr][3] = c.y;
  }
  float sums[16];
#pragma unroll
  for (int oc = 0; oc < 16; ++oc) {
    const float bias = gb[oc];
    float a00 = bias, a01 = bias, a10 = bias, a11 = bias;
#pragma unroll
    for (int ic = 0; ic < 3; ++ic)
#pragma unroll
    for (int ky = 0; ky < 3; ++ky)
#pragma unroll
    for (int kx = 0; kx < 3; ++kx) {
      const float wv = gw[oc * 27 + ic * 9 + ky * 3 + kx];   // block-uniform -> SGPR
      a00 += wv * win[ic][ky][kx];     a01 += wv * win[ic][ky][kx + 1];
      a10 += wv * win[ic][ky + 1][kx]; a11 += wv * win[ic][ky + 1][kx + 1];
    }
    sums[oc] = fmaxf(a00, 0.f) + fmaxf(a01, 0.f) + fmaxf(a10, 0.f) + fmaxf(a11, 0.f);
  }
  const int lane = t & 63, wid = t >> 6;
#pragma unroll
  for (int oc = 0; oc < 16; ++oc) {
    float s = sums[oc];
    s += __shfl_xor(s, 1);
    s += __shfl_xor(s, 2);
    s += __shfl_xor(s, 4);
    sums[oc] = s;
  }
  if ((lane & 7) == 0) {
    const int slot = wid * 8 + (lane >> 3);
#pragma unroll
    for (int oc = 0; oc < 16; ++oc) red[oc * 33 + slot] = sums[oc];
  }
  __syncthreads();
  if (t < 16) {
    float s = 0.f;
#pragma unroll
    for (int i = 0; i < 32; ++i) s += red[t * 33 + i];
    pooled[(size_t)b * 16 + t] = s * (1.f / 1024.f);
  }
}

// ---------------- K2: router FC + softmax + top-1 + bucketing + prob sums ----------------
__global__ __launch_bounds__(256) void k_router_fc(const float* __restrict__ pooled,
    const float* __restrict__ gwfc, const float* __restrict__ gbfc,
    float* __restrict__ probs_out, int* __restrict__ eidx, float* __restrict__ ew,
    int* __restrict__ counts, int* __restrict__ order, float* __restrict__ psum) {
  __shared__ float ps[4];
  const int t = threadIdx.x;
  const int b = blockIdx.x * 256 + t;
  if (t < 4) ps[t] = 0.f;
  __syncthreads();
  const float* pl = pooled + (size_t)b * 16;
  float l[4];
#pragma unroll
  for (int j = 0; j < 4; ++j) {
    float s = gbfc[j];
#pragma unroll
    for (int i = 0; i < 16; ++i) s += pl[i] * gwfc[j * 16 + i];
    l[j] = s;
  }
  const float mx = fmaxf(fmaxf(l[0], l[1]), fmaxf(l[2], l[3]));
  float ex[4], ssum = 0.f;
#pragma unroll
  for (int j = 0; j < 4; ++j) { ex[j] = expf(l[j] - mx); ssum += ex[j]; }
  const float inv = 1.f / ssum;
  float p[4];
#pragma unroll
  for (int j = 0; j < 4; ++j) p[j] = ex[j] * inv;
  *(float4*)(probs_out + (size_t)b * 4) = make_float4(p[0], p[1], p[2], p[3]);
  int em = 0; float pm = p[0];
#pragma unroll
  for (int j = 1; j < 4; ++j) if (p[j] > pm) { pm = p[j]; em = j; }
  eidx[b] = em; ew[b] = pm;
  const int slot = atomicAdd(&counts[em], 1);
  order[em * B_N + slot] = b;
#pragma unroll
  for (int j = 0; j < 4; ++j) atomicAdd(&ps[j], p[j]);
  __syncthreads();
  if (t < 4) atomicAdd(&psum[t], ps[t]);
}

// ---- conv1 A-fragment gather from ic-interleaved fp32 image (R6 measured-best) ----
__device__ __forceinline__ short8 gather_a(const float* __restrict__ base,
                                           const int* goff, bool isq1, bool isq3) {
  float v[8];
#pragma unroll
  for (int t4 = 0; t4 < 4; ++t4) {
    v[2 * t4]     = base[goff[t4]];
    v[2 * t4 + 1] = base[goff[t4] + 1];
  }
  const float pv = base[102];          // patch: p=9 (row 1, c 0) for q==1 lanes
  v[1] = isq1 ? pv : v[1];
  v[3] = isq3 ? 0.f : v[3];            // p>=27 zero padding (q==3, j>=3)
  v[4] = isq3 ? 0.f : v[4];
  v[5] = isq3 ? 0.f : v[5];
  v[6] = isq3 ? 0.f : v[6];
  v[7] = isq3 ? 0.f : v[7];
  union { unsigned u[4]; short8 s; } r;
#pragma unroll
  for (int j = 0; j < 4; ++j) {
    const unsigned lo = (__float_as_uint(v[2 * j]) + 0x8000u) >> 16;        // rnd-half-up bf16
    const unsigned hi = (__float_as_uint(v[2 * j + 1]) + 0x8000u) & 0xffff0000u;
    r.u[j] = lo | hi;
  }
  return r.s;
}

// ---------------- K3: conv1 MFMA (im2col, fp32-staged x) -> h1 bf16 LDS -> conv2 MFMA -> h2 bf16 ----------------
__global__ __launch_bounds__(256, 3) void k_experts_conv(const float* __restrict__ x,
    const unsigned short* __restrict__ w1c, const float* __restrict__ b1g,
    const unsigned short* __restrict__ w2r, const float* __restrict__ b2g,
    const int* __restrict__ eidx, unsigned short* __restrict__ h2b) {
  __shared__ __align__(16) float xpi[3572];                  // [34 rows][34 cols][3 ic] +pad, 14288 B
  __shared__ __align__(16) unsigned short h1s[18 * 18 * 32]; // 20736 B (reused as h2s fp32 [64][68])
  const int b = blockIdx.x, t = threadIdx.x;
  const int e = __builtin_amdgcn_readfirstlane(eidx[b]);
  {
    uint4 z4 = make_uint4(0, 0, 0, 0);
    uint4* z1 = (uint4*)h1s;
    for (int i = t; i < 1296; i += 256) z1[i] = z4;
    uint4* z2 = (uint4*)xpi;
    for (int i = t; i < 893; i += 256) z2[i] = z4;
  }
  __syncthreads();
  const float4* x4 = (const float4*)(x + (size_t)b * 3072);
  for (int i = t; i < 768; i += 256) {
    float4 v = x4[i];
    int flat = i * 4, ic = flat >> 10, rem = flat & 1023, row = rem >> 5, col = rem & 31;
    float* d = &xpi[(row + 1) * 102 + (col + 1) * 3 + ic];
    d[0] = v.x; d[3] = v.y; d[6] = v.z; d[9] = v.w;
  }
  __syncthreads();
  const int lane = t & 63, wv = t >> 6;
  const int n16 = lane & 15, q = lane >> 4;
  // ---- conv1: MFMA 16x16x32, K=27(+pad), M=pixel col, N=32 oc ----
  {
    const bool isq1 = (q == 1), isq3 = (q == 3);
    const short8 wb0 = *(const short8*)(w1c + (((e * 2 + 0) * 4 + q) * 16 + n16) * 8);
    const short8 wb1 = *(const short8*)(w1c + (((e * 2 + 1) * 4 + q) * 16 + n16) * 8);
    const float bias0 = b1g[e * 32 + n16];
    const float bias1 = b1g[e * 32 + 16 + n16];
    int goff[4];
#pragma unroll
    for (int t4 = 0; t4 < 4; ++t4) {
      const int p0 = q * 8 + 2 * t4;
      const int r = (p0 * 939) >> 13;        // p0/9 for p0<32
      goff[t4] = r * 102 + (p0 - 9 * r);
    }
    for (int pid = 0; pid < 8; ++pid) {
      const int pairid = wv * 8 + pid;
      const int yp = pairid >> 1, xh = pairid & 1;
      const float* baseA = &xpi[(2 * yp) * 102 + (xh * 16 + n16) * 3];
      const short8 afA = gather_a(baseA, goff, isq1, isq3);
      const short8 afB = gather_a(baseA + 102, goff, isq1, isq3);
      f32x4 aA0 = {bias0, bias0, bias0, bias0}, aA1 = {bias1, bias1, bias1, bias1};
      f32x4 aB0 = aA0, aB1 = aA1;
      aA0 = __builtin_amdgcn_mfma_f32_16x16x32_bf16(afA, wb0, aA0, 0, 0, 0);
      aA1 = __builtin_amdgcn_mfma_f32_16x16x32_bf16(afA, wb1, aA1, 0, 0, 0);
      aB0 = __builtin_amdgcn_mfma_f32_16x16x32_bf16(afB, wb0, aB0, 0, 0, 0);
      aB1 = __builtin_amdgcn_mfma_f32_16x16x32_bf16(afB, wb1, aB1, 0, 0, 0);
      // 2x2 maxpool + relu -> h1s[pix][ic] bf16
      const int px = xh * 8 + 2 * q;
      unsigned short* hw = &h1s[((yp + 1) * 18 + (px + 1)) * 32];
      const float p00 = fmaxf(fmaxf(fmaxf(aA0[0], aA0[1]), fmaxf(aB0[0], aB0[1])), 0.f);
      const float p01 = fmaxf(fmaxf(fmaxf(aA0[2], aA0[3]), fmaxf(aB0[2], aB0[3])), 0.f);
      const float p10 = fmaxf(fmaxf(fmaxf(aA1[0], aA1[1]), fmaxf(aB1[0], aB1[1])), 0.f);
      const float p11 = fmaxf(fmaxf(fmaxf(aA1[2], aA1[3]), fmaxf(aB1[2], aB1[3])), 0.f);
      hw[n16]           = (unsigned short)f2bf(p00);
      hw[16 + n16]      = (unsigned short)f2bf(p10);
      hw[32 + n16]      = (unsigned short)f2bf(p01);
      hw[32 + 16 + n16] = (unsigned short)f2bf(p11);
    }
  }
  __syncthreads();
  // ---- conv2: wave = 4 rows x all 64 oc; B streamed from global (L2) with prefetch ----
  {
    const unsigned short* wbase = w2r + (size_t)e * 18432 + n16 * 32 + q * 8;
    float bz[4];
#pragma unroll
    for (int nt = 0; nt < 4; ++nt) bz[nt] = b2g[e * 64 + nt * 16 + n16];
    f32x4 acc[4][4];
#pragma unroll
    for (int mt4 = 0; mt4 < 4; ++mt4)
#pragma unroll
      for (int nt = 0; nt < 4; ++nt) {
        acc[mt4][nt][0] = bz[nt]; acc[mt4][nt][1] = bz[nt];
        acc[mt4][nt][2] = bz[nt]; acc[mt4][nt][3] = bz[nt];
      }
    short8 Bc[4];
#pragma unroll
    for (int nt = 0; nt < 4; ++nt) Bc[nt] = *(const short8*)(wbase + nt * 512);
#pragma unroll
    for (int s = 0; s < 9; ++s) {
      const int ky = s / 3, kx = s % 3;
      short8 Bn[4];
      if (s < 8) {
#pragma unroll
        for (int nt = 0; nt < 4; ++nt)
          Bn[nt] = *(const short8*)(wbase + (s + 1) * 2048 + nt * 512);
      }
#pragma unroll
      for (int mt4 = 0; mt4 < 4; ++mt4) {
        const int mt = wv * 4 + mt4;
        const short8 af = *(const short8*)&h1s[((mt + ky) * 18 + n16 + kx) * 32 + q * 8];
#pragma unroll
        for (int nt = 0; nt < 4; ++nt)
          acc[mt4][nt] = __builtin_amdgcn_mfma_f32_16x16x32_bf16(af, Bc[nt], acc[mt4][nt], 0, 0, 0);
      }
      if (s < 8) {
#pragma unroll
        for (int nt = 0; nt < 4; ++nt) Bc[nt] = Bn[nt];
      }
    }
    __syncthreads();                        // all MFMA reads of h1s done
    float* h2s = (float*)h1s;               // [oc][68]
#pragma unroll
    for (int u2 = 0; u2 < 2; ++u2) {
      const int py = wv * 2 + u2;
#pragma unroll
      for (int nt = 0; nt < 4; ++nt) {
        const f32x4 a = acc[2 * u2][nt], c = acc[2 * u2 + 1][nt];
        float2 pv;
        pv.x = fmaxf(fmaxf(fmaxf(a[0], a[1]), fmaxf(c[0], c[1])), 0.f);
        pv.y = fmaxf(fmaxf(fmaxf(a[2], a[3]), fmaxf(c[2], c[3])), 0.f);
        *(float2*)&h2s[(nt * 16 + n16) * 68 + py * 8 + 2 * q] = pv;
      }
    }
  }
  __syncthreads();
  {
    const float* h2s = (const float*)h1s;
    unsigned short* dst = h2b + (size_t)b * 4096;
#pragma unroll
    for (int j = 0; j < 2; ++j) {
      const int f = 8 * (t + 256 * j);          // flat k = oc*64+py*8+px
      const float* src = &h2s[(f >> 6) * 68 + (f & 63)];
      float4 v0 = *(const float4*)src;
      float4 v1 = *(const float4*)(src + 4);
      unsigned int p0 = f2bf(v0.x) | (f2bf(v0.y) << 16);
      unsigned int p1 = f2bf(v0.z) | (f2bf(v0.w) << 16);
      unsigned int p2 = f2bf(v1.x) | (f2bf(v1.y) << 16);
      unsigned int p3 = f2bf(v1.z) | (f2bf(v1.w) << 16);
      *(uint4*)(dst + f) = make_uint4(p0, p1, p2, p3);
    }
  }
}

// ---------------- K4: bucketed fc1 (M=16, bf16 MFMA) + relu + fc2 fp32 + aux, scaled write ----------------
__global__ __launch_bounds__(256) void k_fc(const unsigned short* __restrict__ h2b,
    const unsigned short* __restrict__ w1r, const float* __restrict__ b1g,
    const float* __restrict__ w2g, const float* __restrict__ b2g,
    const int* __restrict__ counts, const int* __restrict__ order,
    const float* __restrict__ ew, const float* __restrict__ psum,
    float* __restrict__ outp) {
  const int bid = blockIdx.x;
  if (bid == 0 && threadIdx.x == 0) {        // aux loss (before any early-exit)
    float a = 0.f;
#pragma unroll
    for (int j = 0; j < 4; ++j) {
      const float mp = psum[j] * (1.f / 4096.f) - 0.25f;
      a += mp * mp;
    }
    outp[57344] = a * 0.25f;
  }
  const int e = bid >> 8, tile = bid & 255;
  const int n = counts[e];
  const int base = tile * 16;
  if (base >= n) return;
  const int t = threadIdx.x;
  __shared__ int sb[16];
  __shared__ float wgt[16];
  __shared__ __align__(16) unsigned short As[16][264];   // 16 samples x 256 k, +8 pad
  __shared__ float f1s[16 * 132];
  if (t < 16) {
    const int idx = base + t;
    const int s = order[e * B_N + ((idx < n) ? idx : base)];
    sb[t] = s; wgt[t] = ew[s];
  }
  __syncthreads();
  const int lane = t & 63, wv = t >> 6;
  const int n16 = lane & 15, q = lane >> 4;
  const int oc0 = wv * 32 + n16;           // n-tile 2*wv
  const int oc1 = wv * 32 + 16 + n16;      // n-tile 2*wv+1
  const unsigned short* wb0 = w1r + ((size_t)(e * 128 + oc0)) * 4096 + q * 8;
  const unsigned short* wb1 = w1r + ((size_t)(e * 128 + oc1)) * 4096 + q * 8;
  f32x4 acc0 = {0.f, 0.f, 0.f, 0.f}, acc1 = {0.f, 0.f, 0.f, 0.f};
  const int ldrow = t >> 4, ldseg = t & 15;
  for (int kc = 0; kc < 4096; kc += 256) {
    {
      const unsigned short* src = h2b + (size_t)sb[ldrow] * 4096 + kc;
      uint4 v0 = *(const uint4*)(src + ldseg * 8);
      uint4 v1 = *(const uint4*)(src + (ldseg + 16) * 8);
      *(uint4*)&As[ldrow][ldseg * 8] = v0;
      *(uint4*)&As[ldrow][(ldseg + 16) * 8] = v1;
    }
    __syncthreads();
#pragma unroll
    for (int ks = 0; ks < 8; ++ks) {
      const short8 af = *(const short8*)&As[n16][ks * 32 + q * 8];   // A[m=n16][k]
      const short8 bf0 = *(const short8*)(wb0 + kc + ks * 32);       // B[k][n=oc0]
      const short8 bf1 = *(const short8*)(wb1 + kc + ks * 32);
      acc0 = __builtin_amdgcn_mfma_f32_16x16x32_bf16(af, bf0, acc0, 0, 0, 0);
      acc1 = __builtin_amdgcn_mfma_f32_16x16x32_bf16(af, bf1, acc1, 0, 0, 0);
    }
    __syncthreads();
  }
  // C layout: row m = q*4+r (sample), col = n16 (oc)
  const float* b1 = b1g + e * 128;
  const float bb0 = b1[oc0], bb1 = b1[oc1];
#pragma unroll
  for (int r = 0; r < 4; ++r) {
    const int m = q * 4 + r;
    f1s[m * 132 + oc0] = fmaxf(acc0[r] + bb0, 0.f);
    f1s[m * 132 + oc1] = fmaxf(acc1[r] + bb1, 0.f);
  }
  __syncthreads();
  int m = n - base; if (m > 16) m = 16;
  if (t < 160) {
    const int r = t / 10, o = t - r * 10;
    if (r < m) {
      const float* w2 = w2g + (e * 10 + o) * 128;
      float s = b2g[e * 10 + o];
#pragma unroll 8
      for (int c = 0; c < 128; ++c) s += f1s[r * 132 + c] * w2[c];
      outp[(size_t)sb[r] * 10 + o] = s * wgt[r];
    }
  }
}

extern "C" void kernel_launch(void* const* d_in, const int* in_sizes, int n_in,
                              void* d_out, int out_size, void* d_ws, size_t ws_size,
                              hipStream_t stream) {
  const float* x        = (const float*)d_in[0];
  const float* gw_conv  = (const float*)d_in[1];
  const float* gb_conv  = (const float*)d_in[2];
  const float* gw_fc    = (const float*)d_in[3];
  const float* gb_fc    = (const float*)d_in[4];
  const float* ew_conv1 = (const float*)d_in[5];
  const float* eb_conv1 = (const float*)d_in[6];
  const float* ew_conv2 = (const float*)d_in[7];
  const float* eb_conv2 = (const float*)d_in[8];
  const float* ew_fc1   = (const float*)d_in[9];
  const float* eb_fc1   = (const float*)d_in[10];
  const float* ew_fc2   = (const float*)d_in[11];
  const float* eb_fc2   = (const float*)d_in[12];
  float* out = (float*)d_out;
  float* ws  = (float*)d_ws;

  unsigned short* h2b = (unsigned short*)(ws + H2B_OFF);
  float* pooled = ws + POOLED_OFF;
  int*   eidx   = (int*)(ws + EIDX_OFF);
  float* ew     = ws + EW_OFF;
  int*   order  = (int*)(ws + ORDER_OFF);
  int*   counts = (int*)(ws + CNT_OFF);
  float* psum   = ws + PSUM_OFF;
  unsigned short* w2r = (unsigned short*)(ws + W2R_OFF);
  unsigned short* w1r = (unsigned short*)(ws + W1R_OFF);
  unsigned short* w1c = (unsigned short*)(ws + W1C_OFF);

  k_repack_all<<<2352, 256, 0, stream>>>(ew_fc1, w1r, ew_conv2, w2r, ew_conv1, w1c, counts);
  k_router_conv<<<4096, 256, 0, stream>>>(x, gw_conv, gb_conv, pooled);
  k_router_fc<<<16, 256, 0, stream>>>(pooled, gw_fc, gb_fc, out + 40960, eidx, ew,
                                      counts, order, psum);
  k_experts_conv<<<4096, 256, 0, stream>>>(x, w1c, eb_conv1, w2r, eb_conv2,
                                           eidx, h2b);
  k_fc<<<1024, 256, 0, stream>>>(h2b, w1r, eb_fc1, ew_fc2, eb_fc2,
                                 counts, order, ew, psum, out);
}

// Round 9
// 311.781 us; speedup vs baseline: 1.1861x; 1.0085x over previous
//
#include <hip/hip_runtime.h>
#include <hip/hip_bf16.h>
#include <cstdint>
#include <cstddef>

#define B_N 4096
typedef short short8 __attribute__((ext_vector_type(8)));
typedef float f32x4 __attribute__((ext_vector_type(4)));

// ws layout (float units)
static constexpr size_t H2B_OFF    = 0;                                  // 4096*4096 ushort
static constexpr size_t POOLED_OFF = 8388608;                            // B*16 f
static constexpr size_t EIDX_OFF   = POOLED_OFF + (size_t)B_N * 16;      // B int
static constexpr size_t EW_OFF     = EIDX_OFF + B_N;                     // B f
static constexpr size_t ORDER_OFF  = EW_OFF + B_N;                       // 4*B int
static constexpr size_t CNT_OFF    = ORDER_OFF + (size_t)4 * B_N;        // 4 int
static constexpr size_t PSUM_OFF   = CNT_OFF + 4;                        // 4 f
static constexpr size_t W2R_OFF    = PSUM_OFF + 4;                       // 73728 ushort = 36864 f
static constexpr size_t W1R_OFF    = W2R_OFF + 36864;                    // 2097152 ushort = 1048576 f
static constexpr size_t W1C_OFF    = W1R_OFF + 1048576;                  // 4096 ushort = 2048 f

__device__ __forceinline__ unsigned int f2bf(float f) {
  unsigned int u = __float_as_uint(f);
  return (u + 0x7fffu + ((u >> 16) & 1u)) >> 16;   // RNE bf16
}
__device__ __forceinline__ unsigned int pkbf(float lo, float hi) {
  float2 f; f.x = lo; f.y = hi;
  __hip_bfloat162 b = __float22bfloat162_rn(f);     // v_cvt_pk_bf16_f32
  union { __hip_bfloat162 b; unsigned u; } c; c.b = b; return c.u;
}

// ---------------- K1: router conv (fp32, SGPR weights) MERGED with weight repacks ----------------
__global__ __launch_bounds__(256) void k_front(const float* __restrict__ x,
    const float* __restrict__ gw, const float* __restrict__ gb, float* __restrict__ pooled,
    const float* __restrict__ wfc1, unsigned short* __restrict__ w1r,
    const float* __restrict__ wc2, unsigned short* __restrict__ w2r,
    const float* __restrict__ wc1, unsigned short* __restrict__ w1c,
    int* __restrict__ counts) {
  __shared__ __align__(16) float xpad[3 * 34 * 34];   // 13872 B (rc path only)
  __shared__ float red[16 * 33];
  const int bid = blockIdx.x, t = threadIdx.x;
  if (bid >= 4096) {            // ---- repack paths ----
    const int rb = bid - 4096;
    if (rb < 2048) {
      const int i = rb * 256 + t;                    // float4 index
      const float4 v = ((const float4*)wfc1)[i];
      ushort4 u;
      u.x = (unsigned short)f2bf(v.x); u.y = (unsigned short)f2bf(v.y);
      u.z = (unsigned short)f2bf(v.z); u.w = (unsigned short)f2bf(v.w);
      *(ushort4*)(w1r + 4 * (size_t)i) = u;
    } else if (rb < 2336) {
      if (rb == 2048 && t < 8) counts[t] = 0;        // counts[4] + psum[4]
      const int i = (rb - 2048) * 256 + t;
      if (i < 4 * 9 * 64 * 32) {
        const int ic = i & 31, j = i >> 5;
        const int oc = j & 63, j2 = j >> 6;
        const int s = j2 % 9, e = j2 / 9;
        w2r[i] = (unsigned short)f2bf(wc2[(((size_t)e * 64 + oc) * 32 + ic) * 9 + s]);
      }
    } else {
      const int i = (rb - 2336) * 256 + t;           // [0, 4096)
      if (i < 4096) {
        const int j = i & 7, n16 = (i >> 3) & 15, q = (i >> 7) & 3, nt = (i >> 9) & 1, e = i >> 10;
        const int k = q * 8 + j;
        float v = 0.f;
        if (k < 27) {
          const int ky = k / 9, c = k % 9, kx = c / 3, ic = c % 3;
          v = wc1[((e * 32 + nt * 16 + n16) * 3 + ic) * 9 + ky * 3 + kx];
        }
        w1c[i] = (unsigned short)f2bf(v);
      }
    }
    return;
  }
  // ---- router conv path ----
  const int b = bid;
  for (int i = t; i < 867; i += 256) ((uint4*)xpad)[i] = make_uint4(0, 0, 0, 0);
  __syncthreads();
  const float4* x4 = (const float4*)(x + (size_t)b * 3072);
  for (int i = t; i < 768; i += 256) {
    float4 v = x4[i];
    int flat = i * 4, ic = flat >> 10, rem = flat & 1023, row = rem >> 5, col = rem & 31;
    float* d = &xpad[ic * 1156 + (row + 1) * 34 + (col + 1)];
    d[0] = v.x; d[1] = v.y; d[2] = v.z; d[3] = v.w;
  }
  __syncthreads();
  const int ty = t >> 4, tx = t & 15;
  float win[3][4][4];
#pragma unroll
  for (int ic = 0; ic < 3; ++ic)
#pragma unroll
  for (int rr = 0; rr < 4; ++rr) {
    const float2* p = (const float2*)&xpad[ic * 1156 + (2 * ty + rr) * 34 + 2 * tx];
    float2 a = p[0], c = p[1];
    win[ic][rr][0] = a.x; win[ic][rr][1] = a.y; win[ic][rr][2] = c.x; win[ic][rr][3] = c.y;
  }
  float sums[16];
#pragma unroll
  for (int oc = 0; oc < 16; ++oc) {
    const float bias = gb[oc];
    float a00 = bias, a01 = bias, a10 = bias, a11 = bias;
#pragma unroll
    for (int ic = 0; ic < 3; ++ic)
#pragma unroll
    for (int ky = 0; ky < 3; ++ky)
#pragma unroll
    for (int kx = 0; kx < 3; ++kx) {
      const float wv = gw[oc * 27 + ic * 9 + ky * 3 + kx];   // block-uniform -> SGPR
      a00 += wv * win[ic][ky][kx];     a01 += wv * win[ic][ky][kx + 1];
      a10 += wv * win[ic][ky + 1][kx]; a11 += wv * win[ic][ky + 1][kx + 1];
    }
    sums[oc] = fmaxf(a00, 0.f) + fmaxf(a01, 0.f) + fmaxf(a10, 0.f) + fmaxf(a11, 0.f);
  }
  const int lane = t & 63, wid = t >> 6;
#pragma unroll
  for (int oc = 0; oc < 16; ++oc) {
    float s = sums[oc];
    s += __shfl_xor(s, 1);
    s += __shfl_xor(s, 2);
    s += __shfl_xor(s, 4);
    sums[oc] = s;
  }
  if ((lane & 7) == 0) {
    const int slot = wid * 8 + (lane >> 3);
#pragma unroll
    for (int oc = 0; oc < 16; ++oc) red[oc * 33 + slot] = sums[oc];
  }
  __syncthreads();
  if (t < 16) {
    float s = 0.f;
#pragma unroll
    for (int i = 0; i < 32; ++i) s += red[t * 33 + i];
    pooled[(size_t)b * 16 + t] = s * (1.f / 1024.f);
  }
}

// ---------------- K2: router FC + softmax + top-1 + bucketing + prob sums ----------------
__global__ __launch_bounds__(256) void k_router_fc(const float* __restrict__ pooled,
    const float* __restrict__ gwfc, const float* __restrict__ gbfc,
    float* __restrict__ probs_out, int* __restrict__ eidx, float* __restrict__ ew,
    int* __restrict__ counts, int* __restrict__ order, float* __restrict__ psum) {
  __shared__ float ps[4];
  const int t = threadIdx.x;
  const int b = blockIdx.x * 256 + t;
  if (t < 4) ps[t] = 0.f;
  __syncthreads();
  const float* pl = pooled + (size_t)b * 16;
  float l[4];
#pragma unroll
  for (int j = 0; j < 4; ++j) {
    float s = gbfc[j];
#pragma unroll
    for (int i = 0; i < 16; ++i) s += pl[i] * gwfc[j * 16 + i];
    l[j] = s;
  }
  const float mx = fmaxf(fmaxf(l[0], l[1]), fmaxf(l[2], l[3]));
  float ex[4], ssum = 0.f;
#pragma unroll
  for (int j = 0; j < 4; ++j) { ex[j] = expf(l[j] - mx); ssum += ex[j]; }
  const float inv = 1.f / ssum;
  float p[4];
#pragma unroll
  for (int j = 0; j < 4; ++j) p[j] = ex[j] * inv;
  *(float4*)(probs_out + (size_t)b * 4) = make_float4(p[0], p[1], p[2], p[3]);
  int em = 0; float pm = p[0];
#pragma unroll
  for (int j = 1; j < 4; ++j) if (p[j] > pm) { pm = p[j]; em = j; }
  eidx[b] = em; ew[b] = pm;
  const int slot = atomicAdd(&counts[em], 1);
  order[em * B_N + slot] = b;
#pragma unroll
  for (int j = 0; j < 4; ++j) atomicAdd(&ps[j], p[j]);
  __syncthreads();
  if (t < 4) atomicAdd(&psum[t], ps[t]);
}

// ---- conv1 A-fragment gather from ic-interleaved fp32 image (packed bf16 cvt) ----
__device__ __forceinline__ short8 gather_a(const float* __restrict__ base,
                                           const int* goff, bool isq1, bool isq3) {
  const float a0 = base[goff[0]];
  float       a1 = base[goff[0] + 1];
  const float b0 = base[goff[1]], b1 = base[goff[1] + 1];
  const float c0 = base[goff[2]], c1 = base[goff[2] + 1];
  const float d0 = base[goff[3]], d1 = base[goff[3] + 1];
  a1 = isq1 ? base[102] : a1;          // patch: p=9 (row 1, c 0) for q==1 lanes
  union { unsigned u[4]; short8 s; } r;
  r.u[0] = pkbf(a0, a1);
  r.u[1] = pkbf(b0, isq3 ? 0.f : b1);  // p>=27 zero padding (q==3)
  r.u[2] = isq3 ? 0u : pkbf(c0, c1);
  r.u[3] = isq3 ? 0u : pkbf(d0, d1);
  return r.s;
}

// ---------------- K3: conv1 MFMA (im2col) -> h1 bf16 LDS (36-stride, bank-clean) -> conv2 MFMA -> h2 bf16 ----------------
__global__ __launch_bounds__(256, 3) void k_experts_conv(const float* __restrict__ x,
    const unsigned short* __restrict__ w1c, const float* __restrict__ b1g,
    const unsigned short* __restrict__ w2r, const float* __restrict__ b2g,
    const int* __restrict__ eidx, unsigned short* __restrict__ h2b) {
  __shared__ __align__(16) float xpi[3572];                  // [34 rows][34 cols][3 ic] +pad, 14288 B
  __shared__ __align__(16) unsigned short h1s[18 * 18 * 36]; // 23328 B, pixel stride 36 u16 (bank pad)
  const int b = blockIdx.x, t = threadIdx.x;
  const int e = __builtin_amdgcn_readfirstlane(eidx[b]);
  {
    uint4 z4 = make_uint4(0, 0, 0, 0);
    uint4* z1 = (uint4*)h1s;
    for (int i = t; i < 1458; i += 256) z1[i] = z4;
    uint4* z2 = (uint4*)xpi;
    for (int i = t; i < 893; i += 256) z2[i] = z4;
  }
  __syncthreads();
  const float4* x4 = (const float4*)(x + (size_t)b * 3072);
  for (int i = t; i < 768; i += 256) {
    float4 v = x4[i];
    int flat = i * 4, ic = flat >> 10, rem = flat & 1023, row = rem >> 5, col = rem & 31;
    float* d = &xpi[(row + 1) * 102 + (col + 1) * 3 + ic];
    d[0] = v.x; d[3] = v.y; d[6] = v.z; d[9] = v.w;
  }
  __syncthreads();
  const int lane = t & 63, wv = t >> 6;
  const int n16 = lane & 15, q = lane >> 4;
  // ---- conv1: MFMA 16x16x32, K=27(+pad), M=pixel col, N=32 oc ----
  {
    const bool isq1 = (q == 1), isq3 = (q == 3);
    const short8 wb0 = *(const short8*)(w1c + (((e * 2 + 0) * 4 + q) * 16 + n16) * 8);
    const short8 wb1 = *(const short8*)(w1c + (((e * 2 + 1) * 4 + q) * 16 + n16) * 8);
    const float bias0 = b1g[e * 32 + n16];
    const float bias1 = b1g[e * 32 + 16 + n16];
    int goff[4];
#pragma unroll
    for (int t4 = 0; t4 < 4; ++t4) {
      const int p0 = q * 8 + 2 * t4;
      const int r = (p0 * 939) >> 13;        // p0/9 for p0<32
      goff[t4] = r * 102 + (p0 - 9 * r);
    }
    for (int pid = 0; pid < 8; ++pid) {
      const int pairid = wv * 8 + pid;
      const int yp = pairid >> 1, xh = pairid & 1;
      const float* baseA = &xpi[(2 * yp) * 102 + (xh * 16 + n16) * 3];
      const short8 afA = gather_a(baseA, goff, isq1, isq3);
      const short8 afB = gather_a(baseA + 102, goff, isq1, isq3);
      f32x4 aA0 = {bias0, bias0, bias0, bias0}, aA1 = {bias1, bias1, bias1, bias1};
      f32x4 aB0 = aA0, aB1 = aA1;
      aA0 = __builtin_amdgcn_mfma_f32_16x16x32_bf16(afA, wb0, aA0, 0, 0, 0);
      aA1 = __builtin_amdgcn_mfma_f32_16x16x32_bf16(afA, wb1, aA1, 0, 0, 0);
      aB0 = __builtin_amdgcn_mfma_f32_16x16x32_bf16(afB, wb0, aB0, 0, 0, 0);
      aB1 = __builtin_amdgcn_mfma_f32_16x16x32_bf16(afB, wb1, aB1, 0, 0, 0);
      // 2x2 maxpool + relu -> h1s[pix][ic] bf16 (pixel stride 36)
      const int px = xh * 8 + 2 * q;
      unsigned short* hw = &h1s[((yp + 1) * 18 + (px + 1)) * 36];
      const float p00 = fmaxf(fmaxf(fmaxf(aA0[0], aA0[1]), fmaxf(aB0[0], aB0[1])), 0.f);
      const float p01 = fmaxf(fmaxf(fmaxf(aA0[2], aA0[3]), fmaxf(aB0[2], aB0[3])), 0.f);
      const float p10 = fmaxf(fmaxf(fmaxf(aA1[0], aA1[1]), fmaxf(aB1[0], aB1[1])), 0.f);
      const float p11 = fmaxf(fmaxf(fmaxf(aA1[2], aA1[3]), fmaxf(aB1[2], aB1[3])), 0.f);
      hw[n16]           = (unsigned short)f2bf(p00);
      hw[16 + n16]      = (unsigned short)f2bf(p10);
      hw[36 + n16]      = (unsigned short)f2bf(p01);
      hw[36 + 16 + n16] = (unsigned short)f2bf(p11);
    }
  }
  __syncthreads();
  // ---- conv2: wave = 4 rows x all 64 oc; B streamed from global (L2) with prefetch ----
  {
    const unsigned short* wbase = w2r + (size_t)e * 18432 + n16 * 32 + q * 8;
    float bz[4];
#pragma unroll
    for (int nt = 0; nt < 4; ++nt) bz[nt] = b2g[e * 64 + nt * 16 + n16];
    f32x4 acc[4][4];
#pragma unroll
    for (int mt4 = 0; mt4 < 4; ++mt4)
#pragma unroll
      for (int nt = 0; nt < 4; ++nt) {
        acc[mt4][nt][0] = bz[nt]; acc[mt4][nt][1] = bz[nt];
        acc[mt4][nt][2] = bz[nt]; acc[mt4][nt][3] = bz[nt];
      }
    short8 Bc[4];
#pragma unroll
    for (int nt = 0; nt < 4; ++nt) Bc[nt] = *(const short8*)(wbase + nt * 512);
#pragma unroll
    for (int s = 0; s < 9; ++s) {
      const int ky = s / 3, kx = s % 3;
      short8 Bn[4];
      if (s < 8) {
#pragma unroll
        for (int nt = 0; nt < 4; ++nt)
          Bn[nt] = *(const short8*)(wbase + (s + 1) * 2048 + nt * 512);
      }
#pragma unroll
      for (int mt4 = 0; mt4 < 4; ++mt4) {
        const int mt = wv * 4 + mt4;
        const short8 af = *(const short8*)&h1s[((mt + ky) * 18 + n16 + kx) * 36 + q * 8];
#pragma unroll
        for (int nt = 0; nt < 4; ++nt)
          acc[mt4][nt] = __builtin_amdgcn_mfma_f32_16x16x32_bf16(af, Bc[nt], acc[mt4][nt], 0, 0, 0);
      }
      if (s < 8) {
#pragma unroll
        for (int nt = 0; nt < 4; ++nt) Bc[nt] = Bn[nt];
      }
    }
    __syncthreads();                        // all MFMA reads of h1s done
    float* h2s = (float*)h1s;               // [oc][68]
#pragma unroll
    for (int u2 = 0; u2 < 2; ++u2) {
      const int py = wv * 2 + u2;
#pragma unroll
      for (int nt = 0; nt < 4; ++nt) {
        const f32x4 a = acc[2 * u2][nt], c = acc[2 * u2 + 1][nt];
        float2 pv;
        pv.x = fmaxf(fmaxf(fmaxf(a[0], a[1]), fmaxf(c[0], c[1])), 0.f);
        pv.y = fmaxf(fmaxf(fmaxf(a[2], a[3]), fmaxf(c[2], c[3])), 0.f);
        *(float2*)&h2s[(nt * 16 + n16) * 68 + py * 8 + 2 * q] = pv;
      }
    }
  }
  __syncthreads();
  {
    const float* h2s = (const float*)h1s;
    unsigned short* dst = h2b + (size_t)b * 4096;
#pragma unroll
    for (int j = 0; j < 2; ++j) {
      const int f = 8 * (t + 256 * j);          // flat k = oc*64+py*8+px
      const float* src = &h2s[(f >> 6) * 68 + (f & 63)];
      float4 v0 = *(const float4*)src;
      float4 v1 = *(const float4*)(src + 4);
      unsigned int p0 = pkbf(v0.x, v0.y);
      unsigned int p1 = pkbf(v0.z, v0.w);
      unsigned int p2 = pkbf(v1.x, v1.y);
      unsigned int p3 = pkbf(v1.z, v1.w);
      *(uint4*)(dst + f) = make_uint4(p0, p1, p2, p3);
    }
  }
}

// ---------------- K4: bucketed fc1 (M=16, bf16 MFMA, reg-prefetch) + relu + fc2 fp32 + aux ----------------
__global__ __launch_bounds__(256) void k_fc(const unsigned short* __restrict__ h2b,
    const unsigned short* __restrict__ w1r, const float* __restrict__ b1g,
    const float* __restrict__ w2g, const float* __restrict__ b2g,
    const int* __restrict__ counts, const int* __restrict__ order,
    const float* __restrict__ ew, const float* __restrict__ psum,
    float* __restrict__ outp) {
  const int bid = blockIdx.x;
  if (bid == 0 && threadIdx.x == 0) {        // aux loss (before any early-exit)
    float a = 0.f;
#pragma unroll
    for (int j = 0; j < 4; ++j) {
      const float mp = psum[j] * (1.f / 4096.f) - 0.25f;
      a += mp * mp;
    }
    outp[57344] = a * 0.25f;
  }
  const int e = bid >> 8, tile = bid & 255;
  const int n = counts[e];
  const int base = tile * 16;
  if (base >= n) return;
  const int t = threadIdx.x;
  __shared__ int sb[16];
  __shared__ float wgt[16];
  __shared__ __align__(16) unsigned short As[16][280];   // 16 x 256 k, stride 280 (bank-clean)
  __shared__ float f1s[16 * 132];
  if (t < 16) {
    const int idx = base + t;
    const int s = order[e * B_N + ((idx < n) ? idx : base)];
    sb[t] = s; wgt[t] = ew[s];
  }
  __syncthreads();
  const int lane = t & 63, wv = t >> 6;
  const int n16 = lane & 15, q = lane >> 4;
  const int oc0 = wv * 32 + n16;           // n-tile 2*wv
  const int oc1 = wv * 32 + 16 + n16;      // n-tile 2*wv+1
  const unsigned short* wb0 = w1r + ((size_t)(e * 128 + oc0)) * 4096 + q * 8;
  const unsigned short* wb1 = w1r + ((size_t)(e * 128 + oc1)) * 4096 + q * 8;
  f32x4 acc0 = {0.f, 0.f, 0.f, 0.f}, acc1 = {0.f, 0.f, 0.f, 0.f};
  const int ldrow = t >> 4, ldseg = t & 15;
  const unsigned short* asrc = h2b + (size_t)sb[ldrow] * 4096;
  uint4 r0 = *(const uint4*)(asrc + ldseg * 8);            // prefetch kc=0
  uint4 r1 = *(const uint4*)(asrc + (ldseg + 16) * 8);
  for (int kc = 0; kc < 4096; kc += 256) {
    *(uint4*)&As[ldrow][ldseg * 8] = r0;
    *(uint4*)&As[ldrow][(ldseg + 16) * 8] = r1;
    __syncthreads();
    if (kc + 256 < 4096) {                                 // prefetch next chunk (overlaps MFMA)
      r0 = *(const uint4*)(asrc + (kc + 256) + ldseg * 8);
      r1 = *(const uint4*)(asrc + (kc + 256) + (ldseg + 16) * 8);
    }
#pragma unroll
    for (int ks = 0; ks < 8; ++ks) {
      const short8 af = *(const short8*)&As[n16][ks * 32 + q * 8];   // A[m=n16][k]
      const short8 bf0 = *(const short8*)(wb0 + kc + ks * 32);       // B[k][n=oc0]
      const short8 bf1 = *(const short8*)(wb1 + kc + ks * 32);
      acc0 = __builtin_amdgcn_mfma_f32_16x16x32_bf16(af, bf0, acc0, 0, 0, 0);
      acc1 = __builtin_amdgcn_mfma_f32_16x16x32_bf16(af, bf1, acc1, 0, 0, 0);
    }
    __syncthreads();
  }
  // C layout: row m = q*4+r (sample), col = n16 (oc)
  const float* b1 = b1g + e * 128;
  const float bb0 = b1[oc0], bb1 = b1[oc1];
#pragma unroll
  for (int r = 0; r < 4; ++r) {
    const int m = q * 4 + r;
    f1s[m * 132 + oc0] = fmaxf(acc0[r] + bb0, 0.f);
    f1s[m * 132 + oc1] = fmaxf(acc1[r] + bb1, 0.f);
  }
  __syncthreads();
  int m = n - base; if (m > 16) m = 16;
  if (t < 160) {
    const int r = t / 10, o = t - r * 10;
    if (r < m) {
      const float* w2 = w2g + (e * 10 + o) * 128;
      float s = b2g[e * 10 + o];
#pragma unroll 8
      for (int c = 0; c < 128; ++c) s += f1s[r * 132 + c] * w2[c];
      outp[(size_t)sb[r] * 10 + o] = s * wgt[r];
    }
  }
}

extern "C" void kernel_launch(void* const* d_in, const int* in_sizes, int n_in,
                              void* d_out, int out_size, void* d_ws, size_t ws_size,
                              hipStream_t stream) {
  const float* x        = (const float*)d_in[0];
  const float* gw_conv  = (const float*)d_in[1];
  const float* gb_conv  = (const float*)d_in[2];
  const float* gw_fc    = (const float*)d_in[3];
  const float* gb_fc    = (const float*)d_in[4];
  const float* ew_conv1 = (const float*)d_in[5];
  const float* eb_conv1 = (const float*)d_in[6];
  const float* ew_conv2 = (const float*)d_in[7];
  const float* eb_conv2 = (const float*)d_in[8];
  const float* ew_fc1   = (const float*)d_in[9];
  const float* eb_fc1   = (const float*)d_in[10];
  const float* ew_fc2   = (const float*)d_in[11];
  const float* eb_fc2   = (const float*)d_in[12];
  float* out = (float*)d_out;
  float* ws  = (float*)d_ws;

  unsigned short* h2b = (unsigned short*)(ws + H2B_OFF);
  float* pooled = ws + POOLED_OFF;
  int*   eidx   = (int*)(ws + EIDX_OFF);
  float* ew     = ws + EW_OFF;
  int*   order  = (int*)(ws + ORDER_OFF);
  int*   counts = (int*)(ws + CNT_OFF);
  float* psum   = ws + PSUM_OFF;
  unsigned short* w2r = (unsigned short*)(ws + W2R_OFF);
  unsigned short* w1r = (unsigned short*)(ws + W1R_OFF);
  unsigned short* w1c = (unsigned short*)(ws + W1C_OFF);

  k_front<<<6448, 256, 0, stream>>>(x, gw_conv, gb_conv, pooled,
                                    ew_fc1, w1r, ew_conv2, w2r, ew_conv1, w1c, counts);
  k_router_fc<<<16, 256, 0, stream>>>(pooled, gw_fc, gb_fc, out + 40960, eidx, ew,
                                      counts, order, psum);
  k_experts_conv<<<4096, 256, 0, stream>>>(x, w1c, eb_conv1, w2r, eb_conv2,
                                           eidx, h2b);
  k_fc<<<1024, 256, 0, stream>>>(h2b, w1r, eb_fc1, ew_fc2, eb_fc2,
                                 counts, order, ew, psum, out);
}